// Round 1
// baseline (410.336 us; speedup 1.0000x reference)
//
#include <hip/hip_runtime.h>
#include <hip/hip_bf16.h>
#include <stdint.h>

#define M_TOT 16384
#define N_TOT 3072
#define K_TOT 768

typedef __attribute__((ext_vector_type(8))) short short8;
typedef __attribute__((ext_vector_type(4))) float f32x4;

__device__ __forceinline__ unsigned short f2bf(float f) {
    union { float f; unsigned u; } v;
    v.f = f;
    unsigned r = v.u + 0x7FFFu + ((v.u >> 16) & 1u);  // round-to-nearest-even
    return (unsigned short)(r >> 16);
}

// ---------------- kernel 1: x fp32 -> bf16 (vectorized, 8 elems/thread/iter) --
__global__ __launch_bounds__(256) void cvt_x_kernel(const float* __restrict__ x,
                                                    unsigned short* __restrict__ xb,
                                                    int n8) {
    int i = blockIdx.x * blockDim.x + threadIdx.x;
    int stride = gridDim.x * blockDim.x;
    const float4* xv = reinterpret_cast<const float4*>(x);
    uint4* ov = reinterpret_cast<uint4*>(xb);
    for (; i < n8; i += stride) {
        float4 a = xv[2 * i], b = xv[2 * i + 1];
        uint4 o;
        o.x = (unsigned)f2bf(a.x) | ((unsigned)f2bf(a.y) << 16);
        o.y = (unsigned)f2bf(a.z) | ((unsigned)f2bf(a.w) << 16);
        o.z = (unsigned)f2bf(b.x) | ((unsigned)f2bf(b.y) << 16);
        o.w = (unsigned)f2bf(b.z) | ((unsigned)f2bf(b.w) << 16);
        ov[i] = o;
    }
}

// ---------------- kernel 2: W_t[c][r] = kron_permute(A@B)[r][c] + Sparse[r][c]
// W_tilde[(m1*64+n1)][(m2*48+n2)] -> W[(m1*24+m2)][(n1*48+n2)]
// Stored TRANSPOSED (N-major, [3072][768]) so the GEMM gets B^T layout.
__global__ __launch_bounds__(256) void prep_w_kernel(const float* __restrict__ Af,
                                                     const float* __restrict__ Bf,
                                                     const float* __restrict__ Sp,
                                                     unsigned short* __restrict__ Wt) {
    int idx = blockIdx.x * 256 + threadIdx.x;   // grid covers exactly 3072*768
    int r = idx % 768;    // K index of W
    int c = idx / 768;    // N index of W
    int m1 = r / 24, m2 = r - m1 * 24;
    int n1 = c / 48, n2 = c - n1 * 48;
    const float* arow = Af + (size_t)(m1 * 64 + n1) * 64;
    const float* bcol = Bf + (m2 * 48 + n2);
    float acc = Sp[(size_t)r * 3072 + c];
    #pragma unroll
    for (int k = 0; k < 64; ++k)
        acc = fmaf(arow[k], bcol[(size_t)k * 1152], acc);
    Wt[(size_t)c * 768 + r] = f2bf(acc);
}

// ---------------- kernel 3: bf16 MFMA GEMM, m97 structure ---------------------
// A  : [16384][768]  bf16 row-major (x)
// Bt : [3072][768]   bf16 row-major (W transposed)
// C  : [16384][3072] fp32, C = A@Bt^T + bias
__device__ __forceinline__ void gload16(const unsigned short* g, unsigned short* l) {
    __builtin_amdgcn_global_load_lds(
        (const __attribute__((address_space(1))) void*)g,
        (__attribute__((address_space(3))) void*)l, 16, 0, 0);
}

__global__ __launch_bounds__(256) void gemm_bt_kernel(const unsigned short* __restrict__ A,
                                                      const unsigned short* __restrict__ Bt,
                                                      const float* __restrict__ bias,
                                                      float* __restrict__ C) {
    __shared__ unsigned short As[128 * 64];   // [row][k]
    __shared__ unsigned short Bs[128 * 64];   // [col][k]

    const int tid = threadIdx.x;
    const int lane = tid & 63;
    const int wid = tid >> 6;          // 0..3
    const int wr = wid >> 1;           // wave row (0..1)
    const int wc = wid & 1;            // wave col (0..1)

    const int bm = blockIdx.x / (N_TOT / 128);
    const int bn = blockIdx.x % (N_TOT / 128);
    const int brow = bm * 128, bcol = bn * 128;

    // staging: chunk = rnd*256 + tid; row = chunk>>3 (= rnd*32 + tid>>3),
    // koff = (chunk&7)*8; LDS elem offset = rnd*2048 + tid*8 (linear, matches
    // wave-uniform-base + lane*16B rule)
    const int srow = tid >> 3;
    const int skoff = (tid & 7) * 8;

    f32x4 acc[4][4];
    #pragma unroll
    for (int m = 0; m < 4; ++m)
        #pragma unroll
        for (int n = 0; n < 4; ++n)
            acc[m][n] = (f32x4){0.f, 0.f, 0.f, 0.f};

    const int la = lane & 15;           // frag row/col index
    const int lk = (lane >> 4) * 8;     // frag k base

    for (int kt = 0; kt < K_TOT / 64; ++kt) {
        const int k0 = kt * 64;
        __syncthreads();   // previous iteration's LDS readers done
        #pragma unroll
        for (int rnd = 0; rnd < 4; ++rnd) {
            const int row = rnd * 32 + srow;
            gload16(A + (size_t)(brow + row) * K_TOT + k0 + skoff,
                    &As[rnd * 2048 + wid * 512]);
            gload16(Bt + (size_t)(bcol + row) * K_TOT + k0 + skoff,
                    &Bs[rnd * 2048 + wid * 512]);
        }
        __syncthreads();   // drains vmcnt -> staged data visible
        #pragma unroll
        for (int kk = 0; kk < 2; ++kk) {
            short8 af[4], bfr[4];
            #pragma unroll
            for (int m = 0; m < 4; ++m)
                af[m] = *reinterpret_cast<const short8*>(
                    &As[(wr * 64 + m * 16 + la) * 64 + kk * 32 + lk]);
            #pragma unroll
            for (int n = 0; n < 4; ++n)
                bfr[n] = *reinterpret_cast<const short8*>(
                    &Bs[(wc * 64 + n * 16 + la) * 64 + kk * 32 + lk]);
            #pragma unroll
            for (int m = 0; m < 4; ++m)
                #pragma unroll
                for (int n = 0; n < 4; ++n)
                    acc[m][n] = __builtin_amdgcn_mfma_f32_16x16x32_bf16(
                        af[m], bfr[n], acc[m][n], 0, 0, 0);
        }
    }

    // epilogue: C/D layout col = lane&15, row = (lane>>4)*4 + j   [m89]
    const int rgrp = (lane >> 4) * 4;
    #pragma unroll
    for (int n = 0; n < 4; ++n) {
        const int gc = bcol + wc * 64 + n * 16 + la;
        const float bv = bias[gc];
        #pragma unroll
        for (int m = 0; m < 4; ++m) {
            const int gr = brow + wr * 64 + m * 16 + rgrp;
            #pragma unroll
            for (int j = 0; j < 4; ++j)
                C[(size_t)(gr + j) * N_TOT + gc] = acc[m][n][j] + bv;
        }
    }
}

extern "C" void kernel_launch(void* const* d_in, const int* in_sizes, int n_in,
                              void* d_out, int out_size, void* d_ws, size_t ws_size,
                              hipStream_t stream) {
    const float* x    = (const float*)d_in[0];
    const float* Af   = (const float*)d_in[1];  // [2048][64]
    const float* Bf   = (const float*)d_in[2];  // [64][1152]
    const float* Sp   = (const float*)d_in[3];  // [768][3072]
    const float* bias = (const float*)d_in[4];  // [3072]
    float* out = (float*)d_out;

    unsigned short* xb = (unsigned short*)d_ws;                 // 25,165,824 B
    unsigned short* wt = xb + (size_t)M_TOT * K_TOT;            // + 4,718,592 B

    hipLaunchKernelGGL(cvt_x_kernel, dim3(2048), dim3(256), 0, stream,
                       x, xb, M_TOT * K_TOT / 8);
    hipLaunchKernelGGL(prep_w_kernel, dim3((N_TOT * K_TOT) / 256), dim3(256), 0, stream,
                       Af, Bf, Sp, wt);
    hipLaunchKernelGGL(gemm_bt_kernel, dim3((M_TOT / 128) * (N_TOT / 128)), dim3(256),
                       0, stream, xb, wt, bias, out);
}

// Round 2
// 176.563 us; speedup vs baseline: 2.3240x; 2.3240x over previous
//
#include <hip/hip_runtime.h>
#include <hip/hip_bf16.h>
#include <stdint.h>

#define M_TOT 16384
#define N_TOT 3072
#define K_TOT 768

typedef __attribute__((ext_vector_type(8))) short short8;
typedef __attribute__((ext_vector_type(4))) float f32x4;

__device__ __forceinline__ unsigned short f2bf(float f) {
    union { float f; unsigned u; } v;
    v.f = f;
    unsigned r = v.u + 0x7FFFu + ((v.u >> 16) & 1u);  // round-to-nearest-even
    return (unsigned short)(r >> 16);
}

// ---------------- kernel 1: x fp32 -> bf16 (vectorized, 8 elems/thread/iter) --
__global__ __launch_bounds__(256) void cvt_x_kernel(const float* __restrict__ x,
                                                    unsigned short* __restrict__ xb,
                                                    int n8) {
    int i = blockIdx.x * blockDim.x + threadIdx.x;
    int stride = gridDim.x * blockDim.x;
    const float4* xv = reinterpret_cast<const float4*>(x);
    uint4* ov = reinterpret_cast<uint4*>(xb);
    for (; i < n8; i += stride) {
        float4 a = xv[2 * i], b = xv[2 * i + 1];
        uint4 o;
        o.x = (unsigned)f2bf(a.x) | ((unsigned)f2bf(a.y) << 16);
        o.y = (unsigned)f2bf(a.z) | ((unsigned)f2bf(a.w) << 16);
        o.z = (unsigned)f2bf(b.x) | ((unsigned)f2bf(b.y) << 16);
        o.w = (unsigned)f2bf(b.z) | ((unsigned)f2bf(b.w) << 16);
        ov[i] = o;
    }
}

// ---------------- kernel 2a: W_tilde = A @ B  (2048x1152x64, fp32, LDS-tiled) --
// 64x64 output tile per block, K=64 single pass.
__global__ __launch_bounds__(256) void wtilde_gemm_kernel(const float* __restrict__ Af,
                                                          const float* __restrict__ Bf,
                                                          float* __restrict__ Wtmp) {
    __shared__ float As[64][68];   // k-major: As[k][p_local], pad 68 (16B-aligned rows)
    __shared__ float Bs[64][68];   // Bs[k][q_local]
    const int tid = threadIdx.x;
    const int bp = blockIdx.x / 18, bq = blockIdx.x % 18;
    const int p0 = bp * 64, q0 = bq * 64;

    // A tile, stored transposed. Column-gather read (L1 absorbs the strided
    // lines: tile is 16KB), conflict-free LDS writes (lanes p consecutive).
    {
        const int p = tid & 63, kb = tid >> 6;   // kb 0..3
        #pragma unroll
        for (int l = 0; l < 16; ++l) {
            int k = l * 4 + kb;
            As[k][p] = Af[(size_t)(p0 + p) * 64 + k];
        }
    }
    // B tile: coalesced float4 row reads, vector LDS writes.
    {
        #pragma unroll
        for (int l = 0; l < 4; ++l) {
            int idx = l * 256 + tid;
            int k = idx >> 4, c4 = (idx & 15) * 4;
            *reinterpret_cast<f32x4*>(&Bs[k][c4]) =
                *reinterpret_cast<const f32x4*>(&Bf[(size_t)k * 1152 + q0 + c4]);
        }
    }
    __syncthreads();

    float acc[4][4] = {};
    const int rb = (tid >> 4) * 4;   // p_local base
    const int cb = (tid & 15) * 4;   // q_local base
    #pragma unroll
    for (int k = 0; k < 64; ++k) {
        f32x4 a = *reinterpret_cast<const f32x4*>(&As[k][rb]);
        f32x4 b = *reinterpret_cast<const f32x4*>(&Bs[k][cb]);
        #pragma unroll
        for (int i = 0; i < 4; ++i)
            #pragma unroll
            for (int j = 0; j < 4; ++j)
                acc[i][j] = fmaf(a[i], b[j], acc[i][j]);
    }
    #pragma unroll
    for (int i = 0; i < 4; ++i) {
        f32x4 o = {acc[i][0], acc[i][1], acc[i][2], acc[i][3]};
        *reinterpret_cast<f32x4*>(&Wtmp[(size_t)(p0 + rb + i) * 1152 + q0 + cb]) = o;
    }
}

// ---------------- kernel 2b: Kronecker permute + Sparse add + bf16 + transpose
// Wt[n1*48+n2][m1*24+m2] = bf16( W_tilde[m1*64+n1][m2*48+n2] + Sp[r][c] )
// 64r x 64c tile through LDS so reads AND writes coalesce.
__global__ __launch_bounds__(256) void permute_w_kernel(const float* __restrict__ Wtmp,
                                                        const float* __restrict__ Sp,
                                                        unsigned short* __restrict__ Wt) {
    __shared__ float T[64][65];    // T[r_local][c_local], pad kills write-phase conflicts
    const int tid = threadIdx.x;
    const int r0 = (blockIdx.x % 12) * 64;
    const int c0 = (blockIdx.x / 12) * 64;

    #pragma unroll
    for (int l = 0; l < 16; ++l) {
        int i = l * 4 + (tid >> 6);
        int j = tid & 63;
        int r = r0 + i, c = c0 + j;
        int m1 = r / 24, m2 = r - m1 * 24;
        int n1 = c / 48, n2 = c - n1 * 48;
        T[i][j] = Wtmp[(size_t)(m1 * 64 + n1) * 1152 + m2 * 48 + n2]
                + Sp[(size_t)r * 3072 + c];
    }
    __syncthreads();

    // write 16B (8 r-values) per unit; 512 units per tile
    #pragma unroll
    for (int u0 = 0; u0 < 2; ++u0) {
        int u = u0 * 256 + tid;
        int jj = u >> 3;       // c_local
        int ii = u & 7;        // r chunk of 8
        unsigned w[4];
        #pragma unroll
        for (int t = 0; t < 4; ++t) {
            unsigned lo = f2bf(T[ii * 8 + 2 * t][jj]);
            unsigned hi = f2bf(T[ii * 8 + 2 * t + 1][jj]);
            w[t] = lo | (hi << 16);
        }
        uint4 o = {w[0], w[1], w[2], w[3]};
        *reinterpret_cast<uint4*>(&Wt[(size_t)(c0 + jj) * 768 + r0 + ii * 8]) = o;
    }
}

// ---------------- kernel 3: bf16 MFMA GEMM, m97 structure ---------------------
// A  : [16384][768]  bf16 row-major (x)
// Bt : [3072][768]   bf16 row-major (W transposed)
// C  : [16384][3072] fp32, C = A@Bt^T + bias
__device__ __forceinline__ void gload16(const unsigned short* g, unsigned short* l) {
    __builtin_amdgcn_global_load_lds(
        (const __attribute__((address_space(1))) void*)g,
        (__attribute__((address_space(3))) void*)l, 16, 0, 0);
}

__global__ __launch_bounds__(256) void gemm_bt_kernel(const unsigned short* __restrict__ A,
                                                      const unsigned short* __restrict__ Bt,
                                                      const float* __restrict__ bias,
                                                      float* __restrict__ C) {
    __shared__ unsigned short As[128 * 64];   // [row][k]
    __shared__ unsigned short Bs[128 * 64];   // [col][k]

    const int tid = threadIdx.x;
    const int lane = tid & 63;
    const int wid = tid >> 6;          // 0..3
    const int wr = wid >> 1;           // wave row (0..1)
    const int wc = wid & 1;            // wave col (0..1)

    const int bm = blockIdx.x / (N_TOT / 128);
    const int bn = blockIdx.x % (N_TOT / 128);
    const int brow = bm * 128, bcol = bn * 128;

    const int srow = tid >> 3;
    const int skoff = (tid & 7) * 8;

    f32x4 acc[4][4];
    #pragma unroll
    for (int m = 0; m < 4; ++m)
        #pragma unroll
        for (int n = 0; n < 4; ++n)
            acc[m][n] = (f32x4){0.f, 0.f, 0.f, 0.f};

    const int la = lane & 15;           // frag row/col index
    const int lk = (lane >> 4) * 8;     // frag k base

    for (int kt = 0; kt < K_TOT / 64; ++kt) {
        const int k0 = kt * 64;
        __syncthreads();   // previous iteration's LDS readers done
        #pragma unroll
        for (int rnd = 0; rnd < 4; ++rnd) {
            const int row = rnd * 32 + srow;
            gload16(A + (size_t)(brow + row) * K_TOT + k0 + skoff,
                    &As[rnd * 2048 + wid * 512]);
            gload16(Bt + (size_t)(bcol + row) * K_TOT + k0 + skoff,
                    &Bs[rnd * 2048 + wid * 512]);
        }
        __syncthreads();   // drains vmcnt -> staged data visible
        #pragma unroll
        for (int kk = 0; kk < 2; ++kk) {
            short8 af[4], bfr[4];
            #pragma unroll
            for (int m = 0; m < 4; ++m)
                af[m] = *reinterpret_cast<const short8*>(
                    &As[(wr * 64 + m * 16 + la) * 64 + kk * 32 + lk]);
            #pragma unroll
            for (int n = 0; n < 4; ++n)
                bfr[n] = *reinterpret_cast<const short8*>(
                    &Bs[(wc * 64 + n * 16 + la) * 64 + kk * 32 + lk]);
            #pragma unroll
            for (int m = 0; m < 4; ++m)
                #pragma unroll
                for (int n = 0; n < 4; ++n)
                    acc[m][n] = __builtin_amdgcn_mfma_f32_16x16x32_bf16(
                        af[m], bfr[n], acc[m][n], 0, 0, 0);
        }
    }

    // epilogue: C/D layout col = lane&15, row = (lane>>4)*4 + j   [m89]
    const int rgrp = (lane >> 4) * 4;
    #pragma unroll
    for (int n = 0; n < 4; ++n) {
        const int gc = bcol + wc * 64 + n * 16 + la;
        const float bv = bias[gc];
        #pragma unroll
        for (int m = 0; m < 4; ++m) {
            const int gr = brow + wr * 64 + m * 16 + rgrp;
            #pragma unroll
            for (int j = 0; j < 4; ++j)
                C[(size_t)(gr + j) * N_TOT + gc] = acc[m][n][j] + bv;
        }
    }
}

extern "C" void kernel_launch(void* const* d_in, const int* in_sizes, int n_in,
                              void* d_out, int out_size, void* d_ws, size_t ws_size,
                              hipStream_t stream) {
    const float* x    = (const float*)d_in[0];
    const float* Af   = (const float*)d_in[1];  // [2048][64]
    const float* Bf   = (const float*)d_in[2];  // [64][1152]
    const float* Sp   = (const float*)d_in[3];  // [768][3072]
    const float* bias = (const float*)d_in[4];  // [3072]
    float* out = (float*)d_out;

    unsigned short* xb = (unsigned short*)d_ws;                 // 25,165,824 B
    unsigned short* wt = xb + (size_t)M_TOT * K_TOT;            // + 4,718,592 B
    // W_tilde scratch lives in the head of d_out (201 MB); the main GEMM
    // overwrites every byte of d_out afterwards, stream-ordered.
    float* wtmp = (float*)d_out;                                // 9,437,184 B

    hipLaunchKernelGGL(cvt_x_kernel, dim3(2048), dim3(256), 0, stream,
                       x, xb, M_TOT * K_TOT / 8);
    hipLaunchKernelGGL(wtilde_gemm_kernel, dim3(32 * 18), dim3(256), 0, stream,
                       Af, Bf, wtmp);
    hipLaunchKernelGGL(permute_w_kernel, dim3(12 * 48), dim3(256), 0, stream,
                       wtmp, Sp, wt);
    hipLaunchKernelGGL(gemm_bt_kernel, dim3((M_TOT / 128) * (N_TOT / 128)), dim3(256),
                       0, stream, xb, wt, bias, out);
}

// Round 3
// 159.143 us; speedup vs baseline: 2.5784x; 1.1095x over previous
//
#include <hip/hip_runtime.h>
#include <hip/hip_bf16.h>
#include <stdint.h>

#define M_TOT 16384
#define N_TOT 3072
#define K_TOT 768

#define BM 256
#define BN 256
#define BK 32
#define NT (K_TOT / BK)   // 24 K-tiles

typedef __attribute__((ext_vector_type(8))) short short8;
typedef __attribute__((ext_vector_type(4))) float f32x4;

__device__ __forceinline__ unsigned short f2bf(float f) {
    union { float f; unsigned u; } v;
    v.f = f;
    unsigned r = v.u + 0x7FFFu + ((v.u >> 16) & 1u);  // round-to-nearest-even
    return (unsigned short)(r >> 16);
}

// ---------------- kernel 1: x fp32 -> bf16 (vectorized) ----------------------
__global__ __launch_bounds__(256) void cvt_x_kernel(const float* __restrict__ x,
                                                    unsigned short* __restrict__ xb,
                                                    int n8) {
    int i = blockIdx.x * blockDim.x + threadIdx.x;
    int stride = gridDim.x * blockDim.x;
    const float4* xv = reinterpret_cast<const float4*>(x);
    uint4* ov = reinterpret_cast<uint4*>(xb);
    for (; i < n8; i += stride) {
        float4 a = xv[2 * i], b = xv[2 * i + 1];
        uint4 o;
        o.x = (unsigned)f2bf(a.x) | ((unsigned)f2bf(a.y) << 16);
        o.y = (unsigned)f2bf(a.z) | ((unsigned)f2bf(a.w) << 16);
        o.z = (unsigned)f2bf(b.x) | ((unsigned)f2bf(b.y) << 16);
        o.w = (unsigned)f2bf(b.z) | ((unsigned)f2bf(b.w) << 16);
        ov[i] = o;
    }
}

// ---------------- kernel 2a: W_tilde = A @ B (2048x1152x64, fp32) ------------
__global__ __launch_bounds__(256) void wtilde_gemm_kernel(const float* __restrict__ Af,
                                                          const float* __restrict__ Bf,
                                                          float* __restrict__ Wtmp) {
    __shared__ float As[64][68];
    __shared__ float Bs[64][68];
    const int tid = threadIdx.x;
    const int bp = blockIdx.x / 18, bq = blockIdx.x % 18;
    const int p0 = bp * 64, q0 = bq * 64;
    {
        const int p = tid & 63, kb = tid >> 6;
        #pragma unroll
        for (int l = 0; l < 16; ++l) {
            int k = l * 4 + kb;
            As[k][p] = Af[(size_t)(p0 + p) * 64 + k];
        }
    }
    {
        #pragma unroll
        for (int l = 0; l < 4; ++l) {
            int idx = l * 256 + tid;
            int k = idx >> 4, c4 = (idx & 15) * 4;
            *reinterpret_cast<f32x4*>(&Bs[k][c4]) =
                *reinterpret_cast<const f32x4*>(&Bf[(size_t)k * 1152 + q0 + c4]);
        }
    }
    __syncthreads();
    float acc[4][4] = {};
    const int rb = (tid >> 4) * 4;
    const int cb = (tid & 15) * 4;
    #pragma unroll
    for (int k = 0; k < 64; ++k) {
        f32x4 a = *reinterpret_cast<const f32x4*>(&As[k][rb]);
        f32x4 b = *reinterpret_cast<const f32x4*>(&Bs[k][cb]);
        #pragma unroll
        for (int i = 0; i < 4; ++i)
            #pragma unroll
            for (int j = 0; j < 4; ++j)
                acc[i][j] = fmaf(a[i], b[j], acc[i][j]);
    }
    #pragma unroll
    for (int i = 0; i < 4; ++i) {
        f32x4 o = {acc[i][0], acc[i][1], acc[i][2], acc[i][3]};
        *reinterpret_cast<f32x4*>(&Wtmp[(size_t)(p0 + rb + i) * 1152 + q0 + cb]) = o;
    }
}

// ---------------- kernel 2b: Kronecker permute + Sparse + bf16 + transpose ---
__global__ __launch_bounds__(256) void permute_w_kernel(const float* __restrict__ Wtmp,
                                                        const float* __restrict__ Sp,
                                                        unsigned short* __restrict__ Wt) {
    __shared__ float T[64][65];
    const int tid = threadIdx.x;
    const int r0 = (blockIdx.x % 12) * 64;
    const int c0 = (blockIdx.x / 12) * 64;
    #pragma unroll
    for (int l = 0; l < 16; ++l) {
        int i = l * 4 + (tid >> 6);
        int j = tid & 63;
        int r = r0 + i, c = c0 + j;
        int m1 = r / 24, m2 = r - m1 * 24;
        int n1 = c / 48, n2 = c - n1 * 48;
        T[i][j] = Wtmp[(size_t)(m1 * 64 + n1) * 1152 + m2 * 48 + n2]
                + Sp[(size_t)r * 3072 + c];
    }
    __syncthreads();
    #pragma unroll
    for (int u0 = 0; u0 < 2; ++u0) {
        int u = u0 * 256 + tid;
        int jj = u >> 3;
        int ii = u & 7;
        unsigned w[4];
        #pragma unroll
        for (int t = 0; t < 4; ++t) {
            unsigned lo = f2bf(T[ii * 8 + 2 * t][jj]);
            unsigned hi = f2bf(T[ii * 8 + 2 * t + 1][jj]);
            w[t] = lo | (hi << 16);
        }
        uint4 o = {w[0], w[1], w[2], w[3]};
        *reinterpret_cast<uint4*>(&Wt[(size_t)(c0 + jj) * 768 + r0 + ii * 8]) = o;
    }
}

// ---------------- kernel 3: 256x256-tile pipelined bf16 MFMA GEMM ------------
// A  : [16384][768] bf16 row-major; Bt : [3072][768] bf16 row-major
// C = A@Bt^T + bias.  8 waves (2Mx4N), BK=32, 4 LDS buffers, counted vmcnt.
__device__ __forceinline__ void gld16(const void* g, void* l) {
    __builtin_amdgcn_global_load_lds(
        (const __attribute__((address_space(1))) void*)g,
        (__attribute__((address_space(3))) void*)l, 16, 0, 0);
}

__global__ __launch_bounds__(512, 2) void gemm_bt_kernel(const unsigned short* __restrict__ A,
                                                         const unsigned short* __restrict__ Bt,
                                                         const float* __restrict__ bias,
                                                         float* __restrict__ C) {
    // 4 buffers x (A 16KB + B 16KB) = 128 KB
    __shared__ unsigned short As[4][BM * BK];
    __shared__ unsigned short Bs[4][BN * BK];

    const int tid = threadIdx.x;
    const int lane = tid & 63;
    const int wid = tid >> 6;      // 0..7
    const int wr = wid >> 2;       // 0..1  (M half)
    const int wc = wid & 3;        // 0..3  (N quarter)

    // XCD-aware swizzle: 768 blocks = 8 XCDs x 96
    const int wg = (blockIdx.x & 7) * 96 + (blockIdx.x >> 3);
    const int bm = wg / (N_TOT / BN), bn = wg % (N_TOT / BN);
    const int brow = bm * BM, bcol = bn * BN;

    // ---- staging geometry (linear LDS dest, pre-swizzled global source) ----
    // dest byte d = tid*16 (+8192 for rows 128..255); row = d>>6, phys slot =
    // (d>>4)&3.  Logical slot = phys ^ ((row>>1)&3)  ->  source byte-in-row:
    const int srow = tid >> 2;                                   // 0..127
    const int soff = (((tid & 3) ^ ((tid >> 3) & 3)) << 4);      // bytes
    const char* pA = (const char*)A + ((size_t)(brow + srow) * K_TOT) * 2 + soff;
    const char* pB = (const char*)Bt + ((size_t)(bcol + srow) * K_TOT) * 2 + soff;
    const size_t row128 = (size_t)128 * K_TOT * 2;
    const int tid16 = tid * 16;

#define STAGE_AH(u) do { const char* s_ = pA + (size_t)(u) * (BK * 2);           \
        gld16(s_,          (char*)&As[(u) & 3][0] + tid16);                      \
        gld16(s_ + row128, (char*)&As[(u) & 3][0] + tid16 + 8192); } while (0)
#define STAGE_BH(u) do { const char* s_ = pB + (size_t)(u) * (BK * 2);           \
        gld16(s_,          (char*)&Bs[(u) & 3][0] + tid16);                      \
        gld16(s_ + row128, (char*)&Bs[(u) & 3][0] + tid16 + 8192); } while (0)

    // ---- fragment reads: phys byte = row*64 + ((js ^ ((row>>1)&3))<<4) ------
    // row = 16-aligned base + (lane&15), js = lane>>4  ->  lane-constant slot:
    const int la = lane & 15;
    const int swb = (((lane >> 4) ^ ((lane >> 1) & 3)) << 4);   // byte in row
#define FRAG_A(bu, r) (*(const short8*)((const char*)&As[bu][0] + (r) * 64 + swb))
#define FRAG_B(bu, r) (*(const short8*)((const char*)&Bs[bu][0] + (r) * 64 + swb))

#define EPOCH_BARRIER() do {                                                     \
        __builtin_amdgcn_sched_barrier(0);                                       \
        __builtin_amdgcn_s_barrier();                                            \
        __builtin_amdgcn_sched_barrier(0); } while (0)

    f32x4 acc[8][4];
    #pragma unroll
    for (int m = 0; m < 8; ++m)
        #pragma unroll
        for (int n = 0; n < 4; ++n)
            acc[m][n] = (f32x4){0.f, 0.f, 0.f, 0.f};

    // prologue: stage tiles 0,1,2 (12 loads/thread); wait tile 0 (8 in flight)
    STAGE_AH(0); STAGE_BH(0);
    STAGE_AH(1); STAGE_BH(1);
    STAGE_AH(2); STAGE_BH(2);
    asm volatile("s_waitcnt vmcnt(8)" ::: "memory");
    EPOCH_BARRIER();

    const int arow = wr * 128;
    const int bcolw = wc * 64;
    for (int t = 0; t < NT; ++t) {
        const int bu = t & 3;
        short8 a0[4], b0[4];
        // ---- phase A: stage A-half of tile t+3; compute m0-3 x n0-3 --------
        if (t < NT - 3) STAGE_AH(t + 3);
        #pragma unroll
        for (int n = 0; n < 4; ++n) b0[n] = FRAG_B(bu, bcolw + n * 16 + la);
        #pragma unroll
        for (int m = 0; m < 4; ++m) a0[m] = FRAG_A(bu, arow + m * 16 + la);
        __builtin_amdgcn_s_setprio(1);
        #pragma unroll
        for (int m = 0; m < 4; ++m)
            #pragma unroll
            for (int n = 0; n < 4; ++n)
                acc[m][n] = __builtin_amdgcn_mfma_f32_16x16x32_bf16(
                    a0[m], b0[n], acc[m][n], 0, 0, 0);
        __builtin_amdgcn_s_setprio(0);
        // ---- phase B: stage B-half of tile t+3; compute m4-7 x n0-3 --------
        if (t < NT - 3) STAGE_BH(t + 3);
        #pragma unroll
        for (int m = 0; m < 4; ++m) a0[m] = FRAG_A(bu, arow + 64 + m * 16 + la);
        __builtin_amdgcn_s_setprio(1);
        #pragma unroll
        for (int m = 0; m < 4; ++m)
            #pragma unroll
            for (int n = 0; n < 4; ++n)
                acc[4 + m][n] = __builtin_amdgcn_mfma_f32_16x16x32_bf16(
                    a0[m], b0[n], acc[4 + m][n], 0, 0, 0);
        __builtin_amdgcn_s_setprio(0);
        // ---- epoch end: make tile t+1 visible; keep t+2/t+3 in flight ------
        if (t < NT - 1) {
            if (t < NT - 3)       asm volatile("s_waitcnt vmcnt(8)" ::: "memory");
            else if (t == NT - 3) asm volatile("s_waitcnt vmcnt(4)" ::: "memory");
            else                  asm volatile("s_waitcnt vmcnt(0)" ::: "memory");
            EPOCH_BARRIER();
        }
    }

    // ---- epilogue: C/D layout col = lane&15, row = (lane>>4)*4 + j ----------
    const int rg = (lane >> 4) * 4;
    #pragma unroll
    for (int n = 0; n < 4; ++n) {
        const int gc = bcol + bcolw + n * 16 + la;
        const float bv = bias[gc];
        #pragma unroll
        for (int m = 0; m < 8; ++m) {
            const int gr = brow + arow + m * 16 + rg;
            #pragma unroll
            for (int j = 0; j < 4; ++j)
                C[(size_t)(gr + j) * N_TOT + gc] = acc[m][n][j] + bv;
        }
    }
#undef STAGE_AH
#undef STAGE_BH
#undef FRAG_A
#undef FRAG_B
#undef EPOCH_BARRIER
}

extern "C" void kernel_launch(void* const* d_in, const int* in_sizes, int n_in,
                              void* d_out, int out_size, void* d_ws, size_t ws_size,
                              hipStream_t stream) {
    const float* x    = (const float*)d_in[0];
    const float* Af   = (const float*)d_in[1];  // [2048][64]
    const float* Bf   = (const float*)d_in[2];  // [64][1152]
    const float* Sp   = (const float*)d_in[3];  // [768][3072]
    const float* bias = (const float*)d_in[4];  // [3072]
    float* out = (float*)d_out;

    unsigned short* xb = (unsigned short*)d_ws;                 // 25,165,824 B
    unsigned short* wt = xb + (size_t)M_TOT * K_TOT;            // + 4,718,592 B
    // W_tilde scratch in d_out's head; GEMM overwrites all of d_out after.
    float* wtmp = (float*)d_out;                                // 9,437,184 B

    hipLaunchKernelGGL(cvt_x_kernel, dim3(2048), dim3(256), 0, stream,
                       x, xb, M_TOT * K_TOT / 8);
    hipLaunchKernelGGL(wtilde_gemm_kernel, dim3(32 * 18), dim3(256), 0, stream,
                       Af, Bf, wtmp);
    hipLaunchKernelGGL(permute_w_kernel, dim3(12 * 48), dim3(256), 0, stream,
                       wtmp, Sp, wt);
    hipLaunchKernelGGL(gemm_bt_kernel,
                       dim3((M_TOT / BM) * (N_TOT / BN)), dim3(512),
                       0, stream, xb, wt, bias, out);
}

// Round 4
// 153.950 us; speedup vs baseline: 2.6654x; 1.0337x over previous
//
#include <hip/hip_runtime.h>
#include <hip/hip_bf16.h>
#include <stdint.h>

#define M_TOT 16384
#define N_TOT 3072
#define K_TOT 768

#define BM 256
#define BN 256
#define BK 32
#define NT (K_TOT / BK)   // 24 K-tiles

typedef __attribute__((ext_vector_type(8))) short short8;
typedef __attribute__((ext_vector_type(4))) float f32x4;

__device__ __forceinline__ unsigned short f2bf(float f) {
    union { float f; unsigned u; } v;
    v.f = f;
    unsigned r = v.u + 0x7FFFu + ((v.u >> 16) & 1u);  // round-to-nearest-even
    return (unsigned short)(r >> 16);
}

// ---------------- kernel 1: x fp32 -> bf16 (vectorized) ----------------------
__global__ __launch_bounds__(256) void cvt_x_kernel(const float* __restrict__ x,
                                                    unsigned short* __restrict__ xb,
                                                    int n8) {
    int i = blockIdx.x * blockDim.x + threadIdx.x;
    int stride = gridDim.x * blockDim.x;
    const float4* xv = reinterpret_cast<const float4*>(x);
    uint4* ov = reinterpret_cast<uint4*>(xb);
    for (; i < n8; i += stride) {
        float4 a = xv[2 * i], b = xv[2 * i + 1];
        uint4 o;
        o.x = (unsigned)f2bf(a.x) | ((unsigned)f2bf(a.y) << 16);
        o.y = (unsigned)f2bf(a.z) | ((unsigned)f2bf(a.w) << 16);
        o.z = (unsigned)f2bf(b.x) | ((unsigned)f2bf(b.y) << 16);
        o.w = (unsigned)f2bf(b.z) | ((unsigned)f2bf(b.w) << 16);
        ov[i] = o;
    }
}

// ---------------- kernel 2a: W_tilde = A @ B (2048x1152x64, fp32) ------------
__global__ __launch_bounds__(256) void wtilde_gemm_kernel(const float* __restrict__ Af,
                                                          const float* __restrict__ Bf,
                                                          float* __restrict__ Wtmp) {
    __shared__ float As[64][68];
    __shared__ float Bs[64][68];
    const int tid = threadIdx.x;
    const int bp = blockIdx.x / 18, bq = blockIdx.x % 18;
    const int p0 = bp * 64, q0 = bq * 64;
    {
        const int p = tid & 63, kb = tid >> 6;
        #pragma unroll
        for (int l = 0; l < 16; ++l) {
            int k = l * 4 + kb;
            As[k][p] = Af[(size_t)(p0 + p) * 64 + k];
        }
    }
    {
        #pragma unroll
        for (int l = 0; l < 4; ++l) {
            int idx = l * 256 + tid;
            int k = idx >> 4, c4 = (idx & 15) * 4;
            *reinterpret_cast<f32x4*>(&Bs[k][c4]) =
                *reinterpret_cast<const f32x4*>(&Bf[(size_t)k * 1152 + q0 + c4]);
        }
    }
    __syncthreads();
    float acc[4][4] = {};
    const int rb = (tid >> 4) * 4;
    const int cb = (tid & 15) * 4;
    #pragma unroll
    for (int k = 0; k < 64; ++k) {
        f32x4 a = *reinterpret_cast<const f32x4*>(&As[k][rb]);
        f32x4 b = *reinterpret_cast<const f32x4*>(&Bs[k][cb]);
        #pragma unroll
        for (int i = 0; i < 4; ++i)
            #pragma unroll
            for (int j = 0; j < 4; ++j)
                acc[i][j] = fmaf(a[i], b[j], acc[i][j]);
    }
    #pragma unroll
    for (int i = 0; i < 4; ++i) {
        f32x4 o = {acc[i][0], acc[i][1], acc[i][2], acc[i][3]};
        *reinterpret_cast<f32x4*>(&Wtmp[(size_t)(p0 + rb + i) * 1152 + q0 + cb]) = o;
    }
}

// ---------------- kernel 2b: Kronecker permute + Sparse + bf16 + transpose ---
__global__ __launch_bounds__(256) void permute_w_kernel(const float* __restrict__ Wtmp,
                                                        const float* __restrict__ Sp,
                                                        unsigned short* __restrict__ Wt) {
    __shared__ float T[64][65];
    const int tid = threadIdx.x;
    const int r0 = (blockIdx.x % 12) * 64;
    const int c0 = (blockIdx.x / 12) * 64;
    #pragma unroll
    for (int l = 0; l < 16; ++l) {
        int i = l * 4 + (tid >> 6);
        int j = tid & 63;
        int r = r0 + i, c = c0 + j;
        int m1 = r / 24, m2 = r - m1 * 24;
        int n1 = c / 48, n2 = c - n1 * 48;
        T[i][j] = Wtmp[(size_t)(m1 * 64 + n1) * 1152 + m2 * 48 + n2]
                + Sp[(size_t)r * 3072 + c];
    }
    __syncthreads();
    #pragma unroll
    for (int u0 = 0; u0 < 2; ++u0) {
        int u = u0 * 256 + tid;
        int jj = u >> 3;
        int ii = u & 7;
        unsigned w[4];
        #pragma unroll
        for (int t = 0; t < 4; ++t) {
            unsigned lo = f2bf(T[ii * 8 + 2 * t][jj]);
            unsigned hi = f2bf(T[ii * 8 + 2 * t + 1][jj]);
            w[t] = lo | (hi << 16);
        }
        uint4 o = {w[0], w[1], w[2], w[3]};
        *reinterpret_cast<uint4*>(&Wt[(size_t)(c0 + jj) * 768 + r0 + ii * 8]) = o;
    }
}

// ---------------- kernel 3: 256x256 8-phase pipelined bf16 MFMA GEMM ---------
// A  : [16384][768] bf16 row-major; Bt : [3072][768] bf16 row-major
// C = A@Bt^T + bias.  8 waves (2Mx4N), BK=32, 4 LDS buffers.
// m201-style phases: {reads || stage -> barrier -> lgkmcnt(0) -> 16 MFMA ->
// barrier}, counted vmcnt(8) once per K-tile (never 0 in steady state).
__device__ __forceinline__ void gld16(const void* g, void* l) {
    __builtin_amdgcn_global_load_lds(
        (const __attribute__((address_space(1))) void*)g,
        (__attribute__((address_space(3))) void*)l, 16, 0, 0);
}

__global__ __launch_bounds__(512, 2) void gemm_bt_kernel(const unsigned short* __restrict__ A,
                                                         const unsigned short* __restrict__ Bt,
                                                         const float* __restrict__ bias,
                                                         float* __restrict__ C) {
    // 4 buffers x (A 16KB + B 16KB) = 128 KB
    __shared__ unsigned short As[4][BM * BK];
    __shared__ unsigned short Bs[4][BN * BK];

    const int tid = threadIdx.x;
    const int lane = tid & 63;
    const int wid = tid >> 6;      // 0..7
    const int wr = wid >> 2;       // 0..1  (M half)
    const int wc = wid & 3;        // 0..3  (N quarter)

    // XCD-aware swizzle: 768 blocks = 8 XCDs x 96; consecutive inner idx share
    // bm (A-panel stays in the XCD's L2).
    const int wg = (blockIdx.x & 7) * 96 + (blockIdx.x >> 3);
    const int bm = wg / (N_TOT / BN), bn = wg % (N_TOT / BN);
    const int brow = bm * BM, bcol = bn * BN;

    // ---- staging geometry (linear LDS dest, pre-swizzled global source) ----
    // phys slot = logical slot ^ ((row>>1)&3)  (16B slots, 64B rows)
    const int srow = tid >> 2;                                   // 0..127
    const int soff = (((tid & 3) ^ ((tid >> 3) & 3)) << 4);      // bytes
    const char* pA = (const char*)A + ((size_t)(brow + srow) * K_TOT) * 2 + soff;
    const char* pB = (const char*)Bt + ((size_t)(bcol + srow) * K_TOT) * 2 + soff;
    const size_t row128 = (size_t)128 * K_TOT * 2;
    const int tid16 = tid * 16;

#define STAGE_AH(u) do { const char* s_ = pA + (size_t)(u) * (BK * 2);           \
        gld16(s_,          (char*)&As[(u) & 3][0] + tid16);                      \
        gld16(s_ + row128, (char*)&As[(u) & 3][0] + tid16 + 8192); } while (0)
#define STAGE_BH(u) do { const char* s_ = pB + (size_t)(u) * (BK * 2);           \
        gld16(s_,          (char*)&Bs[(u) & 3][0] + tid16);                      \
        gld16(s_ + row128, (char*)&Bs[(u) & 3][0] + tid16 + 8192); } while (0)

    // ---- fragment reads: phys byte = row*64 + ((js ^ ((row>>1)&3))<<4) ------
    const int la = lane & 15;
    const int swb = (((lane >> 4) ^ ((lane >> 1) & 3)) << 4);   // byte in row
#define FRAG_A(bu, r) (*(const short8*)((const char*)&As[bu][0] + (r) * 64 + swb))
#define FRAG_B(bu, r) (*(const short8*)((const char*)&Bs[bu][0] + (r) * 64 + swb))

#define LGKM0_FENCE() do {                                                       \
        asm volatile("s_waitcnt lgkmcnt(0)" ::: "memory");                       \
        __builtin_amdgcn_sched_barrier(0); } while (0)

    f32x4 acc[8][4];
    #pragma unroll
    for (int m = 0; m < 8; ++m)
        #pragma unroll
        for (int n = 0; n < 4; ++n)
            acc[m][n] = (f32x4){0.f, 0.f, 0.f, 0.f};

    // prologue: stage tiles 0,1,2 (12 loads/thread); wait tile 0 (8 in flight)
    STAGE_AH(0); STAGE_BH(0);
    STAGE_AH(1); STAGE_BH(1);
    STAGE_AH(2); STAGE_BH(2);
    asm volatile("s_waitcnt vmcnt(8)" ::: "memory");
    __builtin_amdgcn_s_barrier();

    const int arow = wr * 128;
    const int bcolw = wc * 64;
    for (int t = 0; t < NT; ++t) {
        const int bu = t & 3;
        short8 a0[4], b0[4];
        // ================= phase A: quadrant m0-3 x n0-3 =====================
        #pragma unroll
        for (int n = 0; n < 4; ++n) b0[n] = FRAG_B(bu, bcolw + n * 16 + la);
        #pragma unroll
        for (int m = 0; m < 4; ++m) a0[m] = FRAG_A(bu, arow + m * 16 + la);
        if (t < NT - 3) STAGE_AH(t + 3);
        __builtin_amdgcn_s_barrier();
        LGKM0_FENCE();
        __builtin_amdgcn_s_setprio(1);
        #pragma unroll
        for (int m = 0; m < 4; ++m)
            #pragma unroll
            for (int n = 0; n < 4; ++n)
                acc[m][n] = __builtin_amdgcn_mfma_f32_16x16x32_bf16(
                    a0[m], b0[n], acc[m][n], 0, 0, 0);
        __builtin_amdgcn_s_setprio(0);
        __builtin_amdgcn_s_barrier();
        // ================= phase B: quadrant m4-7 x n0-3 =====================
        #pragma unroll
        for (int m = 0; m < 4; ++m) a0[m] = FRAG_A(bu, arow + 64 + m * 16 + la);
        if (t < NT - 3) STAGE_BH(t + 3);
        // counted wait: tile t+1 must be resident after the next barrier;
        // tiles t+2 (4 loads) and t+3 (4 loads) stay in flight.
        if (t < NT - 3)       asm volatile("s_waitcnt vmcnt(8)" ::: "memory");
        else if (t == NT - 3) asm volatile("s_waitcnt vmcnt(4)" ::: "memory");
        else if (t == NT - 2) asm volatile("s_waitcnt vmcnt(0)" ::: "memory");
        __builtin_amdgcn_s_barrier();
        LGKM0_FENCE();
        __builtin_amdgcn_s_setprio(1);
        #pragma unroll
        for (int m = 0; m < 4; ++m)
            #pragma unroll
            for (int n = 0; n < 4; ++n)
                acc[4 + m][n] = __builtin_amdgcn_mfma_f32_16x16x32_bf16(
                    a0[m], b0[n], acc[4 + m][n], 0, 0, 0);
        __builtin_amdgcn_s_setprio(0);
        __builtin_amdgcn_s_barrier();
    }

    // ---- epilogue: C/D layout col = lane&15, row = (lane>>4)*4 + j ----------
    const int rg = (lane >> 4) * 4;
    #pragma unroll
    for (int n = 0; n < 4; ++n) {
        const int gc = bcol + bcolw + n * 16 + la;
        const float bv = bias[gc];
        #pragma unroll
        for (int m = 0; m < 8; ++m) {
            const int gr = brow + arow + m * 16 + rg;
            #pragma unroll
            for (int j = 0; j < 4; ++j)
                C[(size_t)(gr + j) * N_TOT + gc] = acc[m][n][j] + bv;
        }
    }
#undef STAGE_AH
#undef STAGE_BH
#undef FRAG_A
#undef FRAG_B
#undef LGKM0_FENCE
}

extern "C" void kernel_launch(void* const* d_in, const int* in_sizes, int n_in,
                              void* d_out, int out_size, void* d_ws, size_t ws_size,
                              hipStream_t stream) {
    const float* x    = (const float*)d_in[0];
    const float* Af   = (const float*)d_in[1];  // [2048][64]
    const float* Bf   = (const float*)d_in[2];  // [64][1152]
    const float* Sp   = (const float*)d_in[3];  // [768][3072]
    const float* bias = (const float*)d_in[4];  // [3072]
    float* out = (float*)d_out;

    unsigned short* xb = (unsigned short*)d_ws;                 // 25,165,824 B
    unsigned short* wt = xb + (size_t)M_TOT * K_TOT;            // + 4,718,592 B
    // W_tilde scratch in d_out's head; GEMM overwrites all of d_out after.
    float* wtmp = (float*)d_out;                                // 9,437,184 B

    hipLaunchKernelGGL(cvt_x_kernel, dim3(2048), dim3(256), 0, stream,
                       x, xb, M_TOT * K_TOT / 8);
    hipLaunchKernelGGL(wtilde_gemm_kernel, dim3(32 * 18), dim3(256), 0, stream,
                       Af, Bf, wtmp);
    hipLaunchKernelGGL(permute_w_kernel, dim3(12 * 48), dim3(256), 0, stream,
                       wtmp, Sp, wt);
    hipLaunchKernelGGL(gemm_bt_kernel,
                       dim3((M_TOT / BM) * (N_TOT / BN)), dim3(512),
                       0, stream, xb, wt, bias, out);
}